// Round 4
// baseline (856.106 us; speedup 1.0000x reference)
//
#include <hip/hip_runtime.h>
#include <hip/hip_bf16.h>

typedef unsigned char uchar;
typedef __attribute__((ext_vector_type(8))) short bf16x8;
typedef __attribute__((ext_vector_type(4))) float f32x4;

__device__ __forceinline__ unsigned short f2bf(float f) {
  union { float f; unsigned int u; } v; v.f = f;
  unsigned int u = v.u + 0x7fffu + ((v.u >> 16) & 1u);
  return (unsigned short)(u >> 16);
}

__device__ __forceinline__ void async_cp16(void* lds, const void* g) {
  __builtin_amdgcn_global_load_lds(
      (const __attribute__((address_space(1))) unsigned int*)g,
      (__attribute__((address_space(3))) unsigned int*)lds, 16, 0, 0);
}

// ---------------- K1: patch bins px,py per (b,n) ----------------
__global__ void pxpy_kernel(const float* __restrict__ boxes, const int* __restrict__ isz,
                            float* __restrict__ px, float* __restrict__ py) {
  int idx = blockIdx.x * 256 + threadIdx.x;  // < 8192
  int b = idx >> 9;
  float w = (float)isz[b * 4 + 0];
  float h = (float)isz[b * 4 + 1];
  float b0 = boxes[idx * 4 + 0] * w;
  float b1 = boxes[idx * 4 + 1] * h;
  float b2 = boxes[idx * 4 + 2] * w;
  float b3 = boxes[idx * 4 + 3] * h;
  float spw = floorf(w / 11.0f);
  float sph = floorf(h / 11.0f);
  float cx = floorf((b0 + b2) * 0.5f);
  float cy = floorf((b1 + b3) * 0.5f);
  int pxi = 0, pyi = 0;
  bool fx = false, fy = false;
  for (int j = 0; j < 11; ++j) {
    float jf = (float)j;
    if (!fx && jf * spw <= cx && cx <= (jf + 1.0f) * spw) { pxi = j; fx = true; }
    if (!fy && jf * sph <= cy && cy <= (jf + 1.0f) * sph) { pyi = j; fy = true; }
  }
  px[idx] = (float)pxi;
  py[idx] = (float)pyi;
}

// ---------------- K2: distance bins (B,N,N) u8, PERMUTED layout ----------------
// Row r keeps its 512 bytes, but within the row bytes are stored as
// [kc(8)][ln(16)][t(4)] where k = kc*64 + t*16 + ln. This is exactly the order
// attn_fused consumes, so it can load one uchar4 per (kc, r) instead of 4 bytes.
__global__ void bins_kernel(const float* __restrict__ px, const float* __restrict__ py,
                            uchar* __restrict__ bins) {
  int r = blockIdx.x;  // b*512+q
  int j = threadIdx.x; // k
  int b = r >> 9;
  float pxq = px[r], pyq = py[r];
  float dx = px[b * 512 + j] - pxq;
  float dy = py[b * 512 + j] - pyq;
  float d = sqrtf(dx * dx + dy * dy) * 2.0f;
  int off = (j >> 6) * 64 + (j & 15) * 4 + ((j >> 4) & 3);
  bins[(size_t)r * 512 + off] = (uchar)(int)d;
}

// ---------------- K3: LayerNorm -> bf16 ----------------
__global__ __launch_bounds__(256) void ln_kernel(const float* __restrict__ f,
                                                 const float* __restrict__ gamma,
                                                 const float* __restrict__ beta,
                                                 unsigned short* __restrict__ x) {
  const int r = blockIdx.x;
  const int t = threadIdx.x;
  const float* row = f + (size_t)r * 768;
  float e0 = row[t], e1 = row[t + 256], e2 = row[t + 512];
  float s = e0 + e1 + e2;
#pragma unroll
  for (int off = 32; off > 0; off >>= 1) s += __shfl_down(s, off);
  __shared__ float red[4];
  const int wid = t >> 6;
  if ((t & 63) == 0) red[wid] = s;
  __syncthreads();
  float mean = (red[0] + red[1] + red[2] + red[3]) * (1.0f / 768.0f);
  __syncthreads();
  float d0 = e0 - mean, d1 = e1 - mean, d2 = e2 - mean;
  float v = d0 * d0 + d1 * d1 + d2 * d2;
#pragma unroll
  for (int off = 32; off > 0; off >>= 1) v += __shfl_down(v, off);
  if ((t & 63) == 0) red[wid] = v;
  __syncthreads();
  float var = (red[0] + red[1] + red[2] + red[3]) * (1.0f / 768.0f);
  float rs = rsqrtf(var + 1e-5f);
  x[(size_t)r * 768 + t]       = f2bf(d0 * rs * gamma[t] + beta[t]);
  x[(size_t)r * 768 + t + 256] = f2bf(d1 * rs * gamma[t + 256] + beta[t + 256]);
  x[(size_t)r * 768 + t + 512] = f2bf(d2 * rs * gamma[t + 512] + beta[t + 512]);
}

// ---------------- K4: weight prep (bf16 conversion + concat) ----------------
__global__ void wprep_kernel(const float* __restrict__ Wq, const float* __restrict__ Wk,
                             const float* __restrict__ Wv, const float* __restrict__ Wo,
                             const float* __restrict__ bq, const float* __restrict__ bk,
                             const float* __restrict__ bv,
                             unsigned short* __restrict__ wcat, unsigned short* __restrict__ wo,
                             float* __restrict__ bcat) {
  int idx = blockIdx.x * 256 + threadIdx.x;  // < 2359296
  if (idx < 1769472) {
    int n = idx / 768, k = idx % 768;
    float v = (n < 768) ? Wq[n * 768 + k]
            : (n < 1536) ? Wk[(n - 768) * 768 + k]
                         : Wv[(n - 1536) * 768 + k];
    wcat[idx] = f2bf(v);
  } else {
    int j = idx - 1769472;
    wo[j] = f2bf(Wo[j]);
  }
  if (idx < 2304)
    bcat[idx] = (idx < 768) ? bq[idx] : (idx < 1536) ? bk[idx - 768] : bv[idx - 1536];
}

// ---------------- K5/K7: GEMM  C[m,n] = sum_k A[m,k]*Bt[n,k] + bias[n] ----------------
// 128x128 tile, BK=32, 256 threads (2x2 waves of 64x64).
// 2-phase double-buffered global_load_lds staging: issue next K-step's loads into
// the alternate buffer BEFORE the MFMA cluster; ONE barrier per step (its implicit
// vmcnt(0) drain lands after the MFMA has covered most of the load latency).
template <bool OUTF32>
__global__ __launch_bounds__(256) void gemm_bt(const unsigned short* __restrict__ A,
                                               const unsigned short* __restrict__ Bt,
                                               const float* __restrict__ bias,
                                               void* __restrict__ Cout, int K, int ldc) {
  __shared__ unsigned short a_lds[2][128 * 32];
  __shared__ unsigned short b_lds[2][128 * 32];
  const int m0 = blockIdx.x * 128, n0 = blockIdx.y * 128;
  const int tid = threadIdx.x;
  const int lane = tid & 63, wid = tid >> 6;
  const int ln = lane & 15, quad = lane >> 4;
  const int wm = (wid & 1) * 64, wn = (wid >> 1) * 64;
  const int srow = tid >> 2, se0 = (tid & 3) << 3;   // staging coords (c = rep*256+tid)
  f32x4 acc[16] = {};
  const int nk = K >> 5;
  // prologue: stage step 0 into buffer 0
#pragma unroll
  for (int rep = 0; rep < 2; ++rep) {
    int c = rep * 256 + tid;
    int row = c >> 2, e0 = (c & 3) << 3;
    async_cp16(&a_lds[0][c * 8], A + (size_t)(m0 + row) * K + e0);
    async_cp16(&b_lds[0][c * 8], Bt + (size_t)(n0 + row) * K + e0);
  }
  __syncthreads();
  for (int kc = 0; kc < nk; ++kc) {
    const int cur = kc & 1;
    if (kc + 1 < nk) {
      const int k0 = (kc + 1) << 5;
#pragma unroll
      for (int rep = 0; rep < 2; ++rep) {
        int c = rep * 256 + tid;
        int row = c >> 2, e0 = (c & 3) << 3;
        async_cp16(&a_lds[cur ^ 1][c * 8], A + (size_t)(m0 + row) * K + k0 + e0);
        async_cp16(&b_lds[cur ^ 1][c * 8], Bt + (size_t)(n0 + row) * K + k0 + e0);
      }
    }
    bf16x8 af[4], bfr[4];
#pragma unroll
    for (int i = 0; i < 4; ++i)
      af[i] = *(const bf16x8*)&a_lds[cur][(wm + i * 16 + ln) * 32 + quad * 8];
#pragma unroll
    for (int j = 0; j < 4; ++j)
      bfr[j] = *(const bf16x8*)&b_lds[cur][(wn + j * 16 + ln) * 32 + quad * 8];
    __builtin_amdgcn_s_setprio(1);
#pragma unroll
    for (int i = 0; i < 4; ++i)
#pragma unroll
      for (int j = 0; j < 4; ++j)
        acc[i * 4 + j] = __builtin_amdgcn_mfma_f32_16x16x32_bf16(af[i], bfr[j], acc[i * 4 + j], 0, 0, 0);
    __builtin_amdgcn_s_setprio(0);
    __syncthreads();  // drains staging vmcnt + all reads of cur done
  }
  (void)srow; (void)se0;
#pragma unroll
  for (int i = 0; i < 4; ++i)
#pragma unroll
    for (int j = 0; j < 4; ++j)
#pragma unroll
      for (int r = 0; r < 4; ++r) {
        int rr = m0 + wm + i * 16 + quad * 4 + r;
        int cc = n0 + wn + j * 16 + ln;
        float v = acc[i * 4 + j][r] + bias[cc];
        if (OUTF32) ((float*)Cout)[(size_t)rr * ldc + cc] = v;
        else ((unsigned short*)Cout)[(size_t)rr * ldc + cc] = f2bf(v);
      }
}

// ---------------- K6: fused attention ----------------
// scores = softmax(q k^T / 8 + dist_bias) -> att (f32), out_h = scores @ v -> attnout (bf16).
// One block per (b, h, 64-row q tile); 4 waves each own 16 q-rows x 512 cols.
// Round-4 changes vs round-3:
//  * bins consumed as uchar4 words (producer layout permuted): 128 -> 32 global
//    loads per thread in the bias phase.
//  * V staging pairs rows (2si, 2si+1): the V^T scatter packs two k-adjacent bf16
//    into one ds_write_b32 -> 16 -> 8 LDS writes per chunk per thread (2-way banks).
__global__ __launch_bounds__(256) void attn_fused(const unsigned short* __restrict__ qkv,
                                                  const uchar* __restrict__ bins,
                                                  const float* __restrict__ dist_emb,
                                                  float* __restrict__ att,
                                                  unsigned short* __restrict__ attnout) {
  const int bidx = blockIdx.x;
  const int qt = bidx & 7;
  const int h = (bidx >> 3) % 12;
  const int b = bidx / 96;
  __shared__ unsigned short qs[64 * 72];     // Q tile (QK) / P rows (PV, swizzled, wave-private)
  __shared__ unsigned short ks[2][64 * 72];  // K chunks (QK) / V^T chunks (PV, swizzled)
  __shared__ float demb[32];
  const int tid = threadIdx.x;
  const int lane = tid & 63, wid = tid >> 6;
  const int ln = lane & 15, quad = lane >> 4;
  if (tid < 32) demb[tid] = dist_emb[tid * 12 + h];

  // stage Q (linear, stride 72)
  {
    int i0 = tid >> 3, e0 = (tid & 7) * 8;
    *(uint4*)&qs[i0 * 72 + e0] =
        *(const uint4*)(qkv + (size_t)(b * 512 + qt * 64 + i0) * 2304 + h * 64 + e0);
    *(uint4*)&qs[(i0 + 32) * 72 + e0] =
        *(const uint4*)(qkv + (size_t)(b * 512 + qt * 64 + i0 + 32) * 2304 + h * 64 + e0);
  }
  const int si = tid >> 3, se = (tid & 7) * 8;
  const unsigned short* kbase = qkv + (size_t)(b * 512) * 2304 + 768 + h * 64 + se;
  const unsigned short* vbase = qkv + (size_t)(b * 512) * 2304 + 1536 + h * 64 + se;
  // prefetch K chunk 0
  uint4 kr0 = *(const uint4*)(kbase + (size_t)si * 2304);
  uint4 kr1 = *(const uint4*)(kbase + (size_t)(si + 32) * 2304);
  __syncthreads();  // Q + demb visible
  bf16x8 a0 = *(const bf16x8*)&qs[(wid * 16 + ln) * 72 + quad * 8];
  bf16x8 a1 = *(const bf16x8*)&qs[(wid * 16 + ln) * 72 + 32 + quad * 8];
  *(uint4*)&ks[0][si * 72 + se] = kr0;
  *(uint4*)&ks[0][(si + 32) * 72 + se] = kr1;
  __syncthreads();  // K0 visible
  f32x4 acc[32] = {};
  for (int kc = 0; kc < 8; ++kc) {
    const unsigned short* cur = ks[kc & 1];
    if (kc < 7) {
      kr0 = *(const uint4*)(kbase + (size_t)((kc + 1) * 64 + si) * 2304);
      kr1 = *(const uint4*)(kbase + (size_t)((kc + 1) * 64 + si + 32) * 2304);
    }
    __builtin_amdgcn_s_setprio(1);
#pragma unroll
    for (int t = 0; t < 4; ++t) {
      bf16x8 b0 = *(const bf16x8*)&cur[(t * 16 + ln) * 72 + quad * 8];
      bf16x8 b1 = *(const bf16x8*)&cur[(t * 16 + ln) * 72 + 32 + quad * 8];
      acc[kc * 4 + t] = __builtin_amdgcn_mfma_f32_16x16x32_bf16(a0, b0, acc[kc * 4 + t], 0, 0, 0);
      acc[kc * 4 + t] = __builtin_amdgcn_mfma_f32_16x16x32_bf16(a1, b1, acc[kc * 4 + t], 0, 0, 0);
    }
    __builtin_amdgcn_s_setprio(0);
    if (kc < 7) {
      unsigned short* nxt = ks[(kc + 1) & 1];
      *(uint4*)&nxt[si * 72 + se] = kr0;
      *(uint4*)&nxt[(si + 32) * 72 + se] = kr1;
      __syncthreads();
    }
  }
  // prefetch V chunk 0, paired rows (latency hides under softmax)
  uint4 vr0 = *(const uint4*)(vbase + (size_t)(2 * si) * 2304);
  uint4 vr1 = *(const uint4*)(vbase + (size_t)(2 * si + 1) * 2304);

  // bias + softmax. C-layout: lane holds rows quad*4+r, col = 16*tile + ln.
  // bins layout per row: [kc][ln][t] -> one uchar4 per (kc, r).
  const int brow0 = qt * 64 + wid * 16 + quad * 4;
  const uchar* binb = bins + (size_t)b * 512 * 512;
#pragma unroll
  for (int kc8 = 0; kc8 < 8; ++kc8)
#pragma unroll
    for (int r = 0; r < 4; ++r) {
      unsigned int b4 = *(const unsigned int*)&binb[(size_t)(brow0 + r) * 512 + kc8 * 64 + ln * 4];
#pragma unroll
      for (int t = 0; t < 4; ++t) {
        int bin = (b4 >> (8 * t)) & 255;
        acc[kc8 * 4 + t][r] = acc[kc8 * 4 + t][r] * 0.125f + demb[bin];
      }
    }
  float inv[4];
#pragma unroll
  for (int r = 0; r < 4; ++r) {
    float m = -1e30f;
#pragma unroll
    for (int i = 0; i < 32; ++i) m = fmaxf(m, acc[i][r]);
    m = fmaxf(m, __shfl_xor(m, 1));
    m = fmaxf(m, __shfl_xor(m, 2));
    m = fmaxf(m, __shfl_xor(m, 4));
    m = fmaxf(m, __shfl_xor(m, 8));
    float s = 0.f;
#pragma unroll
    for (int i = 0; i < 32; ++i) { float p = __expf(acc[i][r] - m); acc[i][r] = p; s += p; }
    s += __shfl_xor(s, 1); s += __shfl_xor(s, 2); s += __shfl_xor(s, 4); s += __shfl_xor(s, 8);
    inv[r] = 1.0f / s;
  }
#pragma unroll
  for (int i = 0; i < 32; ++i)
#pragma unroll
    for (int r = 0; r < 4; ++r) acc[i][r] *= inv[r];

  // scatter V chunk 0 (ks[0] free: all waves past the kc=6 barrier; kc=7 readers use ks[1])
  {
    const unsigned short* x0 = (const unsigned short*)&vr0;
    const unsigned short* x1 = (const unsigned short*)&vr1;
#pragma unroll
    for (int j = 0; j < 8; ++j) {
      int d = se + j;
      int col = (2 * si) ^ (((d >> 3) & 7) << 3);
      unsigned int pk = (unsigned int)x0[j] | ((unsigned int)x1[j] << 16);
      *(unsigned int*)&ks[0][d * 72 + col] = pk;
    }
  }
  __syncthreads();  // V0 visible
  f32x4 acc_o[4] = {};
  float* ob = att + (size_t)((b * 12 + h) * 512) * 512;
  for (int kc = 0; kc < 8; ++kc) {
    const unsigned short* cur = ks[kc & 1];
    if (kc < 7) {
      vr0 = *(const uint4*)(vbase + (size_t)((kc + 1) * 64 + 2 * si) * 2304);
      vr1 = *(const uint4*)(vbase + (size_t)((kc + 1) * 64 + 2 * si + 1) * 2304);
    }
    // P drop: wave-private rows, swizzled cols; no barrier needed
#pragma unroll
    for (int t = 0; t < 4; ++t)
#pragma unroll
      for (int r = 0; r < 4; ++r) {
        int row = wid * 16 + quad * 4 + r;
        int col = (t * 16 + ln) ^ (((row >> 2) & 7) << 3);
        qs[row * 72 + col] = f2bf(acc[kc * 4 + t][r]);
      }
    __builtin_amdgcn_s_setprio(1);
#pragma unroll
    for (int kk = 0; kk < 2; ++kk) {
      int prow = wid * 16 + ln;
      int pcol = (kk * 32 + quad * 8) ^ (((prow >> 2) & 7) << 3);
      bf16x8 af = *(const bf16x8*)&qs[prow * 72 + pcol];
#pragma unroll
      for (int ct = 0; ct < 4; ++ct) {
        int d = ct * 16 + ln;
        int vcol = (kk * 32 + quad * 8) ^ (((d >> 3) & 7) << 3);
        bf16x8 bg = *(const bf16x8*)&cur[d * 72 + vcol];
        acc_o[ct] = __builtin_amdgcn_mfma_f32_16x16x32_bf16(af, bg, acc_o[ct], 0, 0, 0);
      }
    }
    __builtin_amdgcn_s_setprio(0);
    // att store for this chunk (overlaps next chunk's staging/compute)
#pragma unroll
    for (int t = 0; t < 4; ++t)
#pragma unroll
      for (int r = 0; r < 4; ++r)
        ob[(size_t)(brow0 + r) * 512 + kc * 64 + t * 16 + ln] = acc[kc * 4 + t][r];
    if (kc < 7) {
      unsigned short* nxt = ks[(kc + 1) & 1];
      const unsigned short* x0 = (const unsigned short*)&vr0;
      const unsigned short* x1 = (const unsigned short*)&vr1;
#pragma unroll
      for (int j = 0; j < 8; ++j) {
        int d = se + j;
        int col = (2 * si) ^ (((d >> 3) & 7) << 3);
        unsigned int pk = (unsigned int)x0[j] | ((unsigned int)x1[j] << 16);
        *(unsigned int*)&nxt[d * 72 + col] = pk;
      }
      __syncthreads();
    }
  }
#pragma unroll
  for (int ct = 0; ct < 4; ++ct)
#pragma unroll
    for (int r = 0; r < 4; ++r) {
      int m = b * 512 + qt * 64 + wid * 16 + quad * 4 + r;
      int cc = h * 64 + ct * 16 + ln;
      attnout[(size_t)m * 768 + cc] = f2bf(acc_o[ct][r]);
    }
}

extern "C" void kernel_launch(void* const* d_in, const int* in_sizes, int n_in,
                              void* d_out, int out_size, void* d_ws, size_t ws_size,
                              hipStream_t stream) {
  const float* features = (const float*)d_in[0];
  const float* boxes    = (const float*)d_in[1];
  const int*   isz      = (const int*)d_in[2];
  const float* Wq = (const float*)d_in[3];
  const float* bq = (const float*)d_in[4];
  const float* Wk = (const float*)d_in[5];
  const float* bk = (const float*)d_in[6];
  const float* Wv = (const float*)d_in[7];
  const float* bv = (const float*)d_in[8];
  const float* Wo = (const float*)d_in[9];
  const float* bo = (const float*)d_in[10];
  const float* gamma = (const float*)d_in[11];
  const float* beta  = (const float*)d_in[12];
  const float* dist_emb = (const float*)d_in[13];

  float* out = (float*)d_out;                   // (B,N,D) = 8192*768 f32
  float* att = out + (size_t)8192 * 768;        // (B,H,N,N) f32

  char* w = (char*)d_ws;
  float* px = (float*)w;          w += 8192 * 4;
  float* py = (float*)w;          w += 8192 * 4;
  uchar* bins = (uchar*)w;        w += (size_t)16 * 512 * 512;
  unsigned short* x = (unsigned short*)w;       w += (size_t)8192 * 768 * 2;
  unsigned short* wcat = (unsigned short*)w;    w += (size_t)2304 * 768 * 2;
  unsigned short* wo = (unsigned short*)w;      w += (size_t)768 * 768 * 2;
  float* bcat = (float*)w;                      w += 2304 * 4;
  unsigned short* qkv = (unsigned short*)w;     w += (size_t)8192 * 2304 * 2;
  unsigned short* attnout = (unsigned short*)w; w += (size_t)8192 * 768 * 2;

  pxpy_kernel<<<32, 256, 0, stream>>>(boxes, isz, px, py);
  bins_kernel<<<8192, 512, 0, stream>>>(px, py, bins);
  ln_kernel<<<8192, 256, 0, stream>>>(features, gamma, beta, x);
  wprep_kernel<<<9216, 256, 0, stream>>>(Wq, Wk, Wv, Wo, bq, bk, bv, wcat, wo, bcat);
  gemm_bt<false><<<dim3(64, 18), 256, 0, stream>>>(x, wcat, bcat, qkv, 768, 2304);
  attn_fused<<<1536, 256, 0, stream>>>(qkv, bins, dist_emb, att, attnout);
  gemm_bt<true><<<dim3(64, 6), 256, 0, stream>>>(attnout, wo, bo, out, 768, 768);
}

// Round 5
// 431.179 us; speedup vs baseline: 1.9855x; 1.9855x over previous
//
#include <hip/hip_runtime.h>
#include <hip/hip_bf16.h>

typedef unsigned char uchar;
typedef __attribute__((ext_vector_type(8))) short bf16x8;
typedef __attribute__((ext_vector_type(4))) float f32x4;

__device__ __forceinline__ unsigned short f2bf(float f) {
  union { float f; unsigned int u; } v; v.f = f;
  unsigned int u = v.u + 0x7fffu + ((v.u >> 16) & 1u);
  return (unsigned short)(u >> 16);
}

__device__ __forceinline__ void async_cp16(void* lds, const void* g) {
  __builtin_amdgcn_global_load_lds(
      (const __attribute__((address_space(1))) unsigned int*)g,
      (__attribute__((address_space(3))) unsigned int*)lds, 16, 0, 0);
}

// ---------------- K1: patch bins px,py per (b,n) ----------------
__global__ void pxpy_kernel(const float* __restrict__ boxes, const int* __restrict__ isz,
                            float* __restrict__ px, float* __restrict__ py) {
  int idx = blockIdx.x * 256 + threadIdx.x;  // < 8192
  int b = idx >> 9;
  float w = (float)isz[b * 4 + 0];
  float h = (float)isz[b * 4 + 1];
  float b0 = boxes[idx * 4 + 0] * w;
  float b1 = boxes[idx * 4 + 1] * h;
  float b2 = boxes[idx * 4 + 2] * w;
  float b3 = boxes[idx * 4 + 3] * h;
  float spw = floorf(w / 11.0f);
  float sph = floorf(h / 11.0f);
  float cx = floorf((b0 + b2) * 0.5f);
  float cy = floorf((b1 + b3) * 0.5f);
  int pxi = 0, pyi = 0;
  bool fx = false, fy = false;
  for (int j = 0; j < 11; ++j) {
    float jf = (float)j;
    if (!fx && jf * spw <= cx && cx <= (jf + 1.0f) * spw) { pxi = j; fx = true; }
    if (!fy && jf * sph <= cy && cy <= (jf + 1.0f) * sph) { pyi = j; fy = true; }
  }
  px[idx] = (float)pxi;
  py[idx] = (float)pyi;
}

// ---------------- K2: distance bins (B,N,N) u8 ----------------
__global__ void bins_kernel(const float* __restrict__ px, const float* __restrict__ py,
                            uchar* __restrict__ bins) {
  int r = blockIdx.x;  // b*512+q
  int j = threadIdx.x;
  int b = r >> 9;
  float pxq = px[r], pyq = py[r];
  float dx = px[b * 512 + j] - pxq;
  float dy = py[b * 512 + j] - pyq;
  float d = sqrtf(dx * dx + dy * dy) * 2.0f;
  bins[(size_t)r * 512 + j] = (uchar)(int)d;
}

// ---------------- K3: LayerNorm -> bf16 ----------------
__global__ __launch_bounds__(256) void ln_kernel(const float* __restrict__ f,
                                                 const float* __restrict__ gamma,
                                                 const float* __restrict__ beta,
                                                 unsigned short* __restrict__ x) {
  const int r = blockIdx.x;
  const int t = threadIdx.x;
  const float* row = f + (size_t)r * 768;
  float e0 = row[t], e1 = row[t + 256], e2 = row[t + 512];
  float s = e0 + e1 + e2;
#pragma unroll
  for (int off = 32; off > 0; off >>= 1) s += __shfl_down(s, off);
  __shared__ float red[4];
  const int wid = t >> 6;
  if ((t & 63) == 0) red[wid] = s;
  __syncthreads();
  float mean = (red[0] + red[1] + red[2] + red[3]) * (1.0f / 768.0f);
  __syncthreads();
  float d0 = e0 - mean, d1 = e1 - mean, d2 = e2 - mean;
  float v = d0 * d0 + d1 * d1 + d2 * d2;
#pragma unroll
  for (int off = 32; off > 0; off >>= 1) v += __shfl_down(v, off);
  if ((t & 63) == 0) red[wid] = v;
  __syncthreads();
  float var = (red[0] + red[1] + red[2] + red[3]) * (1.0f / 768.0f);
  float rs = rsqrtf(var + 1e-5f);
  x[(size_t)r * 768 + t]       = f2bf(d0 * rs * gamma[t] + beta[t]);
  x[(size_t)r * 768 + t + 256] = f2bf(d1 * rs * gamma[t + 256] + beta[t + 256]);
  x[(size_t)r * 768 + t + 512] = f2bf(d2 * rs * gamma[t + 512] + beta[t + 512]);
}

// ---------------- K4: weight prep (bf16 conversion + concat) ----------------
__global__ void wprep_kernel(const float* __restrict__ Wq, const float* __restrict__ Wk,
                             const float* __restrict__ Wv, const float* __restrict__ Wo,
                             const float* __restrict__ bq, const float* __restrict__ bk,
                             const float* __restrict__ bv,
                             unsigned short* __restrict__ wcat, unsigned short* __restrict__ wo,
                             float* __restrict__ bcat) {
  int idx = blockIdx.x * 256 + threadIdx.x;  // < 2359296
  if (idx < 1769472) {
    int n = idx / 768, k = idx % 768;
    float v = (n < 768) ? Wq[n * 768 + k]
            : (n < 1536) ? Wk[(n - 768) * 768 + k]
                         : Wv[(n - 1536) * 768 + k];
    wcat[idx] = f2bf(v);
  } else {
    int j = idx - 1769472;
    wo[j] = f2bf(Wo[j]);
  }
  if (idx < 2304)
    bcat[idx] = (idx < 768) ? bq[idx] : (idx < 1536) ? bk[idx - 768] : bv[idx - 1536];
}

// ---------------- K5/K7: GEMM  C[m,n] = sum_k A[m,k]*Bt[n,k] + bias[n] ----------------
// 128x128 tile, BK=32, 256 threads (2x2 waves of 64x64).
// 2-phase double-buffered global_load_lds staging (T3-minimum): issue next K-step's
// loads into the alternate buffer BEFORE the MFMA cluster; one barrier per step.
template <bool OUTF32>
__global__ __launch_bounds__(256) void gemm_bt(const unsigned short* __restrict__ A,
                                               const unsigned short* __restrict__ Bt,
                                               const float* __restrict__ bias,
                                               void* __restrict__ Cout, int K, int ldc) {
  __shared__ unsigned short a_lds[2][128 * 32];
  __shared__ unsigned short b_lds[2][128 * 32];
  const int m0 = blockIdx.x * 128, n0 = blockIdx.y * 128;
  const int tid = threadIdx.x;
  const int lane = tid & 63, wid = tid >> 6;
  const int ln = lane & 15, quad = lane >> 4;
  const int wm = (wid & 1) * 64, wn = (wid >> 1) * 64;
  f32x4 acc[16] = {};
  const int nk = K >> 5;
  // prologue: stage step 0 into buffer 0
#pragma unroll
  for (int rep = 0; rep < 2; ++rep) {
    int c = rep * 256 + tid;
    int row = c >> 2, e0 = (c & 3) << 3;
    async_cp16(&a_lds[0][c * 8], A + (size_t)(m0 + row) * K + e0);
    async_cp16(&b_lds[0][c * 8], Bt + (size_t)(n0 + row) * K + e0);
  }
  __syncthreads();
  for (int kc = 0; kc < nk; ++kc) {
    const int cur = kc & 1;
    if (kc + 1 < nk) {
      const int k0 = (kc + 1) << 5;
#pragma unroll
      for (int rep = 0; rep < 2; ++rep) {
        int c = rep * 256 + tid;
        int row = c >> 2, e0 = (c & 3) << 3;
        async_cp16(&a_lds[cur ^ 1][c * 8], A + (size_t)(m0 + row) * K + k0 + e0);
        async_cp16(&b_lds[cur ^ 1][c * 8], Bt + (size_t)(n0 + row) * K + k0 + e0);
      }
    }
    bf16x8 af[4], bfr[4];
#pragma unroll
    for (int i = 0; i < 4; ++i)
      af[i] = *(const bf16x8*)&a_lds[cur][(wm + i * 16 + ln) * 32 + quad * 8];
#pragma unroll
    for (int j = 0; j < 4; ++j)
      bfr[j] = *(const bf16x8*)&b_lds[cur][(wn + j * 16 + ln) * 32 + quad * 8];
#pragma unroll
    for (int i = 0; i < 4; ++i)
#pragma unroll
      for (int j = 0; j < 4; ++j)
        acc[i * 4 + j] = __builtin_amdgcn_mfma_f32_16x16x32_bf16(af[i], bfr[j], acc[i * 4 + j], 0, 0, 0);
    __syncthreads();  // drains staging vmcnt + all reads of cur done
  }
#pragma unroll
  for (int i = 0; i < 4; ++i)
#pragma unroll
    for (int j = 0; j < 4; ++j)
#pragma unroll
      for (int r = 0; r < 4; ++r) {
        int rr = m0 + wm + i * 16 + quad * 4 + r;
        int cc = n0 + wn + j * 16 + ln;
        float v = acc[i * 4 + j][r] + bias[cc];
        if (OUTF32) ((float*)Cout)[(size_t)rr * ldc + cc] = v;
        else ((unsigned short*)Cout)[(size_t)rr * ldc + cc] = f2bf(v);
      }
}

// ---------------- K6: fused attention (round-3 proven version, reverted) ----------------
// scores = softmax(q k^T / 8 + dist_bias) -> att (f32), out_h = scores @ v -> attnout (bf16).
// One block per (b, h, 64-row q tile); 4 waves each own 16 q-rows x 512 cols.
//  * K and V chunks double-buffered in ks[2] with register prefetch issued before the
//    MFMA cluster -> one barrier per chunk, loads overlap compute.
//  * Scattered LDS writes (V transpose, P drop) XOR-swizzled on the column index.
//  * P buffer (qs) is wave-private rows -> no barrier between P write and read.
//  * att stores interleaved into the PV loop.
// NOTE (round-4 lesson): do NOT restructure the bias loop into deeper unroll nests —
// acc[] must stay statically indexed or the 128-VGPR accumulator spills to scratch
// (VGPR 220->68, FETCH 107MB->1.25GB, 4x slowdown).
__global__ __launch_bounds__(256) void attn_fused(const unsigned short* __restrict__ qkv,
                                                  const uchar* __restrict__ bins,
                                                  const float* __restrict__ dist_emb,
                                                  float* __restrict__ att,
                                                  unsigned short* __restrict__ attnout) {
  const int bidx = blockIdx.x;
  const int qt = bidx & 7;
  const int h = (bidx >> 3) % 12;
  const int b = bidx / 96;
  __shared__ unsigned short qs[64 * 72];     // Q tile (QK) / P rows (PV, swizzled, wave-private)
  __shared__ unsigned short ks[2][64 * 72];  // K chunks (QK) / V^T chunks (PV, swizzled)
  __shared__ float demb[32];
  const int tid = threadIdx.x;
  const int lane = tid & 63, wid = tid >> 6;
  const int ln = lane & 15, quad = lane >> 4;
  if (tid < 32) demb[tid] = dist_emb[tid * 12 + h];

  // stage Q (linear, stride 72)
  {
    int i0 = tid >> 3, e0 = (tid & 7) * 8;
    *(uint4*)&qs[i0 * 72 + e0] =
        *(const uint4*)(qkv + (size_t)(b * 512 + qt * 64 + i0) * 2304 + h * 64 + e0);
    *(uint4*)&qs[(i0 + 32) * 72 + e0] =
        *(const uint4*)(qkv + (size_t)(b * 512 + qt * 64 + i0 + 32) * 2304 + h * 64 + e0);
  }
  const int si = tid >> 3, se = (tid & 7) * 8;
  const unsigned short* kbase = qkv + (size_t)(b * 512) * 2304 + 768 + h * 64 + se;
  const unsigned short* vbase = qkv + (size_t)(b * 512) * 2304 + 1536 + h * 64 + se;
  // prefetch K chunk 0
  uint4 kr0 = *(const uint4*)(kbase + (size_t)si * 2304);
  uint4 kr1 = *(const uint4*)(kbase + (size_t)(si + 32) * 2304);
  __syncthreads();  // Q + demb visible
  bf16x8 a0 = *(const bf16x8*)&qs[(wid * 16 + ln) * 72 + quad * 8];
  bf16x8 a1 = *(const bf16x8*)&qs[(wid * 16 + ln) * 72 + 32 + quad * 8];
  *(uint4*)&ks[0][si * 72 + se] = kr0;
  *(uint4*)&ks[0][(si + 32) * 72 + se] = kr1;
  __syncthreads();  // K0 visible
  f32x4 acc[32] = {};
  for (int kc = 0; kc < 8; ++kc) {
    const unsigned short* cur = ks[kc & 1];
    if (kc < 7) {
      kr0 = *(const uint4*)(kbase + (size_t)((kc + 1) * 64 + si) * 2304);
      kr1 = *(const uint4*)(kbase + (size_t)((kc + 1) * 64 + si + 32) * 2304);
    }
    __builtin_amdgcn_s_setprio(1);
#pragma unroll
    for (int t = 0; t < 4; ++t) {
      bf16x8 b0 = *(const bf16x8*)&cur[(t * 16 + ln) * 72 + quad * 8];
      bf16x8 b1 = *(const bf16x8*)&cur[(t * 16 + ln) * 72 + 32 + quad * 8];
      acc[kc * 4 + t] = __builtin_amdgcn_mfma_f32_16x16x32_bf16(a0, b0, acc[kc * 4 + t], 0, 0, 0);
      acc[kc * 4 + t] = __builtin_amdgcn_mfma_f32_16x16x32_bf16(a1, b1, acc[kc * 4 + t], 0, 0, 0);
    }
    __builtin_amdgcn_s_setprio(0);
    if (kc < 7) {
      unsigned short* nxt = ks[(kc + 1) & 1];
      *(uint4*)&nxt[si * 72 + se] = kr0;
      *(uint4*)&nxt[(si + 32) * 72 + se] = kr1;
      __syncthreads();
    }
  }
  // prefetch V chunk 0 (latency hides under softmax)
  uint4 vr0 = *(const uint4*)(vbase + (size_t)si * 2304);
  uint4 vr1 = *(const uint4*)(vbase + (size_t)(si + 32) * 2304);

  // bias + softmax. C-layout: lane holds rows quad*4+r, col = 16*tile + ln
  const int brow0 = qt * 64 + wid * 16 + quad * 4;
  const uchar* binb = bins + (size_t)b * 512 * 512;
#pragma unroll
  for (int i = 0; i < 32; ++i) {
    int col = (i >> 2) * 64 + (i & 3) * 16 + ln;
#pragma unroll
    for (int r = 0; r < 4; ++r) {
      int bin = binb[(size_t)(brow0 + r) * 512 + col];
      acc[i][r] = acc[i][r] * 0.125f + demb[bin];
    }
  }
  float inv[4];
#pragma unroll
  for (int r = 0; r < 4; ++r) {
    float m = -1e30f;
#pragma unroll
    for (int i = 0; i < 32; ++i) m = fmaxf(m, acc[i][r]);
    m = fmaxf(m, __shfl_xor(m, 1));
    m = fmaxf(m, __shfl_xor(m, 2));
    m = fmaxf(m, __shfl_xor(m, 4));
    m = fmaxf(m, __shfl_xor(m, 8));
    float s = 0.f;
#pragma unroll
    for (int i = 0; i < 32; ++i) { float p = __expf(acc[i][r] - m); acc[i][r] = p; s += p; }
    s += __shfl_xor(s, 1); s += __shfl_xor(s, 2); s += __shfl_xor(s, 4); s += __shfl_xor(s, 8);
    inv[r] = 1.0f / s;
  }
#pragma unroll
  for (int i = 0; i < 32; ++i)
#pragma unroll
    for (int r = 0; r < 4; ++r) acc[i][r] *= inv[r];

  // scatter V chunk 0 (ks[0] free: all waves past the kc=6 barrier; kc=7 readers use ks[1])
  {
    const unsigned short* xs = (const unsigned short*)&vr0;
#pragma unroll
    for (int j = 0; j < 8; ++j) {
      int d = se + j;
      ks[0][d * 72 + (si ^ (((d >> 3) & 7) << 3))] = xs[j];
    }
    xs = (const unsigned short*)&vr1;
#pragma unroll
    for (int j = 0; j < 8; ++j) {
      int d = se + j;
      ks[0][d * 72 + ((si + 32) ^ (((d >> 3) & 7) << 3))] = xs[j];
    }
  }
  __syncthreads();  // V0 visible
  f32x4 acc_o[4] = {};
  float* ob = att + (size_t)((b * 12 + h) * 512) * 512;
  for (int kc = 0; kc < 8; ++kc) {
    const unsigned short* cur = ks[kc & 1];
    if (kc < 7) {
      vr0 = *(const uint4*)(vbase + (size_t)((kc + 1) * 64 + si) * 2304);
      vr1 = *(const uint4*)(vbase + (size_t)((kc + 1) * 64 + si + 32) * 2304);
    }
    // P drop: wave-private rows, swizzled cols; no barrier needed
#pragma unroll
    for (int t = 0; t < 4; ++t)
#pragma unroll
      for (int r = 0; r < 4; ++r) {
        int row = wid * 16 + quad * 4 + r;
        int col = (t * 16 + ln) ^ (((row >> 2) & 7) << 3);
        qs[row * 72 + col] = f2bf(acc[kc * 4 + t][r]);
      }
    __builtin_amdgcn_s_setprio(1);
#pragma unroll
    for (int kk = 0; kk < 2; ++kk) {
      int prow = wid * 16 + ln;
      int pcol = (kk * 32 + quad * 8) ^ (((prow >> 2) & 7) << 3);
      bf16x8 af = *(const bf16x8*)&qs[prow * 72 + pcol];
#pragma unroll
      for (int ct = 0; ct < 4; ++ct) {
        int d = ct * 16 + ln;
        int vcol = (kk * 32 + quad * 8) ^ (((d >> 3) & 7) << 3);
        bf16x8 bg = *(const bf16x8*)&cur[d * 72 + vcol];
        acc_o[ct] = __builtin_amdgcn_mfma_f32_16x16x32_bf16(af, bg, acc_o[ct], 0, 0, 0);
      }
    }
    __builtin_amdgcn_s_setprio(0);
    // att store for this chunk (overlaps next chunk's staging/compute)
#pragma unroll
    for (int t = 0; t < 4; ++t)
#pragma unroll
      for (int r = 0; r < 4; ++r)
        ob[(size_t)(brow0 + r) * 512 + kc * 64 + t * 16 + ln] = acc[kc * 4 + t][r];
    if (kc < 7) {
      unsigned short* nxt = ks[(kc + 1) & 1];
      const unsigned short* xs = (const unsigned short*)&vr0;
#pragma unroll
      for (int j = 0; j < 8; ++j) {
        int d = se + j;
        nxt[d * 72 + (si ^ (((d >> 3) & 7) << 3))] = xs[j];
      }
      xs = (const unsigned short*)&vr1;
#pragma unroll
      for (int j = 0; j < 8; ++j) {
        int d = se + j;
        nxt[d * 72 + ((si + 32) ^ (((d >> 3) & 7) << 3))] = xs[j];
      }
      __syncthreads();
    }
  }
#pragma unroll
  for (int ct = 0; ct < 4; ++ct)
#pragma unroll
    for (int r = 0; r < 4; ++r) {
      int m = b * 512 + qt * 64 + wid * 16 + quad * 4 + r;
      int cc = h * 64 + ct * 16 + ln;
      attnout[(size_t)m * 768 + cc] = f2bf(acc_o[ct][r]);
    }
}

extern "C" void kernel_launch(void* const* d_in, const int* in_sizes, int n_in,
                              void* d_out, int out_size, void* d_ws, size_t ws_size,
                              hipStream_t stream) {
  const float* features = (const float*)d_in[0];
  const float* boxes    = (const float*)d_in[1];
  const int*   isz      = (const int*)d_in[2];
  const float* Wq = (const float*)d_in[3];
  const float* bq = (const float*)d_in[4];
  const float* Wk = (const float*)d_in[5];
  const float* bk = (const float*)d_in[6];
  const float* Wv = (const float*)d_in[7];
  const float* bv = (const float*)d_in[8];
  const float* Wo = (const float*)d_in[9];
  const float* bo = (const float*)d_in[10];
  const float* gamma = (const float*)d_in[11];
  const float* beta  = (const float*)d_in[12];
  const float* dist_emb = (const float*)d_in[13];

  float* out = (float*)d_out;                   // (B,N,D) = 8192*768 f32
  float* att = out + (size_t)8192 * 768;        // (B,H,N,N) f32

  char* w = (char*)d_ws;
  float* px = (float*)w;          w += 8192 * 4;
  float* py = (float*)w;          w += 8192 * 4;
  uchar* bins = (uchar*)w;        w += (size_t)16 * 512 * 512;
  unsigned short* x = (unsigned short*)w;       w += (size_t)8192 * 768 * 2;
  unsigned short* wcat = (unsigned short*)w;    w += (size_t)2304 * 768 * 2;
  unsigned short* wo = (unsigned short*)w;      w += (size_t)768 * 768 * 2;
  float* bcat = (float*)w;                      w += 2304 * 4;
  unsigned short* qkv = (unsigned short*)w;     w += (size_t)8192 * 2304 * 2;
  unsigned short* attnout = (unsigned short*)w; w += (size_t)8192 * 768 * 2;

  pxpy_kernel<<<32, 256, 0, stream>>>(boxes, isz, px, py);
  bins_kernel<<<8192, 512, 0, stream>>>(px, py, bins);
  ln_kernel<<<8192, 256, 0, stream>>>(features, gamma, beta, x);
  wprep_kernel<<<9216, 256, 0, stream>>>(Wq, Wk, Wv, Wo, bq, bk, bv, wcat, wo, bcat);
  gemm_bt<false><<<dim3(64, 18), 256, 0, stream>>>(x, wcat, bcat, qkv, 768, 2304);
  attn_fused<<<1536, 256, 0, stream>>>(qkv, bins, dist_emb, att, attnout);
  gemm_bt<true><<<dim3(64, 6), 256, 0, stream>>>(attnout, wo, bo, out, 768, 768);
}

// Round 6
// 397.741 us; speedup vs baseline: 2.1524x; 1.0841x over previous
//
#include <hip/hip_runtime.h>
#include <hip/hip_bf16.h>

typedef unsigned char uchar;
typedef __attribute__((ext_vector_type(8))) short bf16x8;
typedef __attribute__((ext_vector_type(4))) float f32x4;

__device__ __forceinline__ unsigned short f2bf(float f) {
  union { float f; unsigned int u; } v; v.f = f;
  unsigned int u = v.u + 0x7fffu + ((v.u >> 16) & 1u);
  return (unsigned short)(u >> 16);
}

__device__ __forceinline__ void async_cp16(void* lds, const void* g) {
  __builtin_amdgcn_global_load_lds(
      (const __attribute__((address_space(1))) unsigned int*)g,
      (__attribute__((address_space(3))) unsigned int*)lds, 16, 0, 0);
}

// ---------------- K1: patch bins px,py per (b,n), packed u16 ----------------
__global__ void pxpy_kernel(const float* __restrict__ boxes, const int* __restrict__ isz,
                            unsigned short* __restrict__ ppk) {
  int idx = blockIdx.x * 256 + threadIdx.x;  // < 8192
  int b = idx >> 9;
  float w = (float)isz[b * 4 + 0];
  float h = (float)isz[b * 4 + 1];
  float b0 = boxes[idx * 4 + 0] * w;
  float b1 = boxes[idx * 4 + 1] * h;
  float b2 = boxes[idx * 4 + 2] * w;
  float b3 = boxes[idx * 4 + 3] * h;
  float spw = floorf(w / 11.0f);
  float sph = floorf(h / 11.0f);
  float cx = floorf((b0 + b2) * 0.5f);
  float cy = floorf((b1 + b3) * 0.5f);
  int pxi = 0, pyi = 0;
  bool fx = false, fy = false;
  for (int j = 0; j < 11; ++j) {
    float jf = (float)j;
    if (!fx && jf * spw <= cx && cx <= (jf + 1.0f) * spw) { pxi = j; fx = true; }
    if (!fy && jf * sph <= cy && cy <= (jf + 1.0f) * sph) { pyi = j; fy = true; }
  }
  ppk[idx] = (unsigned short)(pxi | (pyi << 8));
}

// ---------------- K3: LayerNorm -> bf16 ----------------
__global__ __launch_bounds__(256) void ln_kernel(const float* __restrict__ f,
                                                 const float* __restrict__ gamma,
                                                 const float* __restrict__ beta,
                                                 unsigned short* __restrict__ x) {
  const int r = blockIdx.x;
  const int t = threadIdx.x;
  const float* row = f + (size_t)r * 768;
  float e0 = row[t], e1 = row[t + 256], e2 = row[t + 512];
  float s = e0 + e1 + e2;
#pragma unroll
  for (int off = 32; off > 0; off >>= 1) s += __shfl_down(s, off);
  __shared__ float red[4];
  const int wid = t >> 6;
  if ((t & 63) == 0) red[wid] = s;
  __syncthreads();
  float mean = (red[0] + red[1] + red[2] + red[3]) * (1.0f / 768.0f);
  __syncthreads();
  float d0 = e0 - mean, d1 = e1 - mean, d2 = e2 - mean;
  float v = d0 * d0 + d1 * d1 + d2 * d2;
#pragma unroll
  for (int off = 32; off > 0; off >>= 1) v += __shfl_down(v, off);
  if ((t & 63) == 0) red[wid] = v;
  __syncthreads();
  float var = (red[0] + red[1] + red[2] + red[3]) * (1.0f / 768.0f);
  float rs = rsqrtf(var + 1e-5f);
  x[(size_t)r * 768 + t]       = f2bf(d0 * rs * gamma[t] + beta[t]);
  x[(size_t)r * 768 + t + 256] = f2bf(d1 * rs * gamma[t + 256] + beta[t + 256]);
  x[(size_t)r * 768 + t + 512] = f2bf(d2 * rs * gamma[t + 512] + beta[t + 512]);
}

// ---------------- K4: weight prep (bf16 conversion + concat) ----------------
__global__ void wprep_kernel(const float* __restrict__ Wq, const float* __restrict__ Wk,
                             const float* __restrict__ Wv, const float* __restrict__ Wo,
                             const float* __restrict__ bq, const float* __restrict__ bk,
                             const float* __restrict__ bv,
                             unsigned short* __restrict__ wcat, unsigned short* __restrict__ wo,
                             float* __restrict__ bcat) {
  int idx = blockIdx.x * 256 + threadIdx.x;  // < 2359296
  if (idx < 1769472) {
    int n = idx / 768, k = idx % 768;
    float v = (n < 768) ? Wq[n * 768 + k]
            : (n < 1536) ? Wk[(n - 768) * 768 + k]
                         : Wv[(n - 1536) * 768 + k];
    wcat[idx] = f2bf(v);
  } else {
    int j = idx - 1769472;
    wo[j] = f2bf(Wo[j]);
  }
  if (idx < 2304)
    bcat[idx] = (idx < 768) ? bq[idx] : (idx < 1536) ? bk[idx - 768] : bv[idx - 1536];
}

// ---------------- K5/K7: GEMM  C[m,n] = sum_k A[m,k]*Bt[n,k] + bias[n] ----------------
// 128x128 tile, BK=32, 256 threads (2x2 waves of 64x64).
// 2-phase double-buffered global_load_lds staging (proven +11us in round 5).
template <bool OUTF32>
__global__ __launch_bounds__(256) void gemm_bt(const unsigned short* __restrict__ A,
                                               const unsigned short* __restrict__ Bt,
                                               const float* __restrict__ bias,
                                               void* __restrict__ Cout, int K, int ldc) {
  __shared__ unsigned short a_lds[2][128 * 32];
  __shared__ unsigned short b_lds[2][128 * 32];
  const int m0 = blockIdx.x * 128, n0 = blockIdx.y * 128;
  const int tid = threadIdx.x;
  const int lane = tid & 63, wid = tid >> 6;
  const int ln = lane & 15, quad = lane >> 4;
  const int wm = (wid & 1) * 64, wn = (wid >> 1) * 64;
  f32x4 acc[16] = {};
  const int nk = K >> 5;
  // prologue: stage step 0 into buffer 0
#pragma unroll
  for (int rep = 0; rep < 2; ++rep) {
    int c = rep * 256 + tid;
    int row = c >> 2, e0 = (c & 3) << 3;
    async_cp16(&a_lds[0][c * 8], A + (size_t)(m0 + row) * K + e0);
    async_cp16(&b_lds[0][c * 8], Bt + (size_t)(n0 + row) * K + e0);
  }
  __syncthreads();
  for (int kc = 0; kc < nk; ++kc) {
    const int cur = kc & 1;
    if (kc + 1 < nk) {
      const int k0 = (kc + 1) << 5;
#pragma unroll
      for (int rep = 0; rep < 2; ++rep) {
        int c = rep * 256 + tid;
        int row = c >> 2, e0 = (c & 3) << 3;
        async_cp16(&a_lds[cur ^ 1][c * 8], A + (size_t)(m0 + row) * K + k0 + e0);
        async_cp16(&b_lds[cur ^ 1][c * 8], Bt + (size_t)(n0 + row) * K + k0 + e0);
      }
    }
    bf16x8 af[4], bfr[4];
#pragma unroll
    for (int i = 0; i < 4; ++i)
      af[i] = *(const bf16x8*)&a_lds[cur][(wm + i * 16 + ln) * 32 + quad * 8];
#pragma unroll
    for (int j = 0; j < 4; ++j)
      bfr[j] = *(const bf16x8*)&b_lds[cur][(wn + j * 16 + ln) * 32 + quad * 8];
#pragma unroll
    for (int i = 0; i < 4; ++i)
#pragma unroll
      for (int j = 0; j < 4; ++j)
        acc[i * 4 + j] = __builtin_amdgcn_mfma_f32_16x16x32_bf16(af[i], bfr[j], acc[i * 4 + j], 0, 0, 0);
    __syncthreads();  // drains staging vmcnt + all reads of cur done
  }
#pragma unroll
  for (int i = 0; i < 4; ++i)
#pragma unroll
    for (int j = 0; j < 4; ++j)
#pragma unroll
      for (int r = 0; r < 4; ++r) {
        int rr = m0 + wm + i * 16 + quad * 4 + r;
        int cc = n0 + wn + j * 16 + ln;
        float v = acc[i * 4 + j][r] + bias[cc];
        if (OUTF32) ((float*)Cout)[(size_t)rr * ldc + cc] = v;
        else ((unsigned short*)Cout)[(size_t)rr * ldc + cc] = f2bf(v);
      }
}

// ---------------- K6: fused attention ----------------
// scores = softmax(q k^T / 8 + dist_bias) -> att (f32), out_h = scores @ v -> attnout (bf16).
// One block per (b, h, 64-row q tile); 4 waves each own 16 q-rows x 512 cols.
// Round-6: bias via 441-entry LDS LUT of demb[bin(dx,dy)] (dx,dy in [-10,10]),
// built once per block; per-token (px,py) packed u16 staged in LDS (1 KB).
// Replaces 128 global ubyte bins loads/thread with 1 add + LDS gather each,
// and deletes the bins_kernel + its 4 MB write / ~48 MB reads entirely.
// NOTE (round-4 lesson): acc[] bias loop structure must stay `for i {for r}`
// with static acc[i][r] indexing or the 128-VGPR accumulator spills to scratch.
__global__ __launch_bounds__(256) void attn_fused(const unsigned short* __restrict__ qkv,
                                                  const unsigned short* __restrict__ ppk,
                                                  const float* __restrict__ dist_emb,
                                                  float* __restrict__ att,
                                                  unsigned short* __restrict__ attnout) {
  const int bidx = blockIdx.x;
  const int qt = bidx & 7;
  const int h = (bidx >> 3) % 12;
  const int b = bidx / 96;
  __shared__ unsigned short qs[64 * 72];     // Q tile (QK) / P rows (PV, swizzled, wave-private)
  __shared__ unsigned short ks[2][64 * 72];  // K chunks (QK) / V^T chunks (PV, swizzled)
  __shared__ float lut[448];                 // demb[bin(dx,dy)] for (dx+10)*21+(dy+10)
  __shared__ unsigned short pklds[512];      // packed px|py<<8 for batch b
  const int tid = threadIdx.x;
  const int lane = tid & 63, wid = tid >> 6;
  const int ln = lane & 15, quad = lane >> 4;
  // build bias LUT: bin = trunc(2*sqrt(dx^2+dy^2)), value = dist_emb[bin*12+h]
  for (int t = tid; t < 441; t += 256) {
    int dx = t / 21 - 10, dy = t % 21 - 10;
    int bin = (int)(sqrtf((float)(dx * dx + dy * dy)) * 2.0f);
    lut[t] = dist_emb[bin * 12 + h];
  }
  if (tid < 64)
    *(uint4*)&pklds[tid * 8] = *(const uint4*)(ppk + (size_t)b * 512 + tid * 8);

  // stage Q (linear, stride 72)
  {
    int i0 = tid >> 3, e0 = (tid & 7) * 8;
    *(uint4*)&qs[i0 * 72 + e0] =
        *(const uint4*)(qkv + (size_t)(b * 512 + qt * 64 + i0) * 2304 + h * 64 + e0);
    *(uint4*)&qs[(i0 + 32) * 72 + e0] =
        *(const uint4*)(qkv + (size_t)(b * 512 + qt * 64 + i0 + 32) * 2304 + h * 64 + e0);
  }
  const int si = tid >> 3, se = (tid & 7) * 8;
  const unsigned short* kbase = qkv + (size_t)(b * 512) * 2304 + 768 + h * 64 + se;
  const unsigned short* vbase = qkv + (size_t)(b * 512) * 2304 + 1536 + h * 64 + se;
  // prefetch K chunk 0
  uint4 kr0 = *(const uint4*)(kbase + (size_t)si * 2304);
  uint4 kr1 = *(const uint4*)(kbase + (size_t)(si + 32) * 2304);
  __syncthreads();  // Q + lut + pklds visible
  bf16x8 a0 = *(const bf16x8*)&qs[(wid * 16 + ln) * 72 + quad * 8];
  bf16x8 a1 = *(const bf16x8*)&qs[(wid * 16 + ln) * 72 + 32 + quad * 8];
  *(uint4*)&ks[0][si * 72 + se] = kr0;
  *(uint4*)&ks[0][(si + 32) * 72 + se] = kr1;
  __syncthreads();  // K0 visible
  f32x4 acc[32] = {};
  for (int kc = 0; kc < 8; ++kc) {
    const unsigned short* cur = ks[kc & 1];
    if (kc < 7) {
      kr0 = *(const uint4*)(kbase + (size_t)((kc + 1) * 64 + si) * 2304);
      kr1 = *(const uint4*)(kbase + (size_t)((kc + 1) * 64 + si + 32) * 2304);
    }
    __builtin_amdgcn_s_setprio(1);
#pragma unroll
    for (int t = 0; t < 4; ++t) {
      bf16x8 b0 = *(const bf16x8*)&cur[(t * 16 + ln) * 72 + quad * 8];
      bf16x8 b1 = *(const bf16x8*)&cur[(t * 16 + ln) * 72 + 32 + quad * 8];
      acc[kc * 4 + t] = __builtin_amdgcn_mfma_f32_16x16x32_bf16(a0, b0, acc[kc * 4 + t], 0, 0, 0);
      acc[kc * 4 + t] = __builtin_amdgcn_mfma_f32_16x16x32_bf16(a1, b1, acc[kc * 4 + t], 0, 0, 0);
    }
    __builtin_amdgcn_s_setprio(0);
    if (kc < 7) {
      unsigned short* nxt = ks[(kc + 1) & 1];
      *(uint4*)&nxt[si * 72 + se] = kr0;
      *(uint4*)&nxt[(si + 32) * 72 + se] = kr1;
      __syncthreads();
    }
  }
  // prefetch V chunk 0 (latency hides under softmax)
  uint4 vr0 = *(const uint4*)(vbase + (size_t)si * 2304);
  uint4 vr1 = *(const uint4*)(vbase + (size_t)(si + 32) * 2304);

  // bias + softmax. C-layout: lane holds rows quad*4+r, col = 16*tile + ln.
  // idx = (pxk-pxq+10)*21 + (pyk-pyq+10) = pxk*21+pyk + cr[r], cr = 220 - pxq*21 - pyq
  const int brow0 = qt * 64 + wid * 16 + quad * 4;
  int cr[4];
#pragma unroll
  for (int r = 0; r < 4; ++r) {
    int pq = pklds[brow0 + r];
    cr[r] = 220 - (pq & 255) * 21 - (pq >> 8);
  }
#pragma unroll
  for (int i = 0; i < 32; ++i) {
    int col = (i >> 2) * 64 + (i & 3) * 16 + ln;
    int pk = pklds[col];
    int base = (pk & 255) * 21 + (pk >> 8);
#pragma unroll
    for (int r = 0; r < 4; ++r) {
      acc[i][r] = acc[i][r] * 0.125f + lut[base + cr[r]];
    }
  }
  float inv[4];
#pragma unroll
  for (int r = 0; r < 4; ++r) {
    float m = -1e30f;
#pragma unroll
    for (int i = 0; i < 32; ++i) m = fmaxf(m, acc[i][r]);
    m = fmaxf(m, __shfl_xor(m, 1));
    m = fmaxf(m, __shfl_xor(m, 2));
    m = fmaxf(m, __shfl_xor(m, 4));
    m = fmaxf(m, __shfl_xor(m, 8));
    float s = 0.f;
#pragma unroll
    for (int i = 0; i < 32; ++i) { float p = __expf(acc[i][r] - m); acc[i][r] = p; s += p; }
    s += __shfl_xor(s, 1); s += __shfl_xor(s, 2); s += __shfl_xor(s, 4); s += __shfl_xor(s, 8);
    inv[r] = 1.0f / s;
  }
#pragma unroll
  for (int i = 0; i < 32; ++i)
#pragma unroll
    for (int r = 0; r < 4; ++r) acc[i][r] *= inv[r];

  // scatter V chunk 0 (ks[0] free: all waves past the kc=6 barrier; kc=7 readers use ks[1])
  {
    const unsigned short* xs = (const unsigned short*)&vr0;
#pragma unroll
    for (int j = 0; j < 8; ++j) {
      int d = se + j;
      ks[0][d * 72 + (si ^ (((d >> 3) & 7) << 3))] = xs[j];
    }
    xs = (const unsigned short*)&vr1;
#pragma unroll
    for (int j = 0; j < 8; ++j) {
      int d = se + j;
      ks[0][d * 72 + ((si + 32) ^ (((d >> 3) & 7) << 3))] = xs[j];
    }
  }
  __syncthreads();  // V0 visible
  f32x4 acc_o[4] = {};
  float* ob = att + (size_t)((b * 12 + h) * 512) * 512;
  for (int kc = 0; kc < 8; ++kc) {
    const unsigned short* cur = ks[kc & 1];
    if (kc < 7) {
      vr0 = *(const uint4*)(vbase + (size_t)((kc + 1) * 64 + si) * 2304);
      vr1 = *(const uint4*)(vbase + (size_t)((kc + 1) * 64 + si + 32) * 2304);
    }
    // P drop: wave-private rows, swizzled cols; no barrier needed
#pragma unroll
    for (int t = 0; t < 4; ++t)
#pragma unroll
      for (int r = 0; r < 4; ++r) {
        int row = wid * 16 + quad * 4 + r;
        int col = (t * 16 + ln) ^ (((row >> 2) & 7) << 3);
        qs[row * 72 + col] = f2bf(acc[kc * 4 + t][r]);
      }
    __builtin_amdgcn_s_setprio(1);
#pragma unroll
    for (int kk = 0; kk < 2; ++kk) {
      int prow = wid * 16 + ln;
      int pcol = (kk * 32 + quad * 8) ^ (((prow >> 2) & 7) << 3);
      bf16x8 af = *(const bf16x8*)&qs[prow * 72 + pcol];
#pragma unroll
      for (int ct = 0; ct < 4; ++ct) {
        int d = ct * 16 + ln;
        int vcol = (kk * 32 + quad * 8) ^ (((d >> 3) & 7) << 3);
        bf16x8 bg = *(const bf16x8*)&cur[d * 72 + vcol];
        acc_o[ct] = __builtin_amdgcn_mfma_f32_16x16x32_bf16(af, bg, acc_o[ct], 0, 0, 0);
      }
    }
    __builtin_amdgcn_s_setprio(0);
    // att store for this chunk (overlaps next chunk's staging/compute)
#pragma unroll
    for (int t = 0; t < 4; ++t)
#pragma unroll
      for (int r = 0; r < 4; ++r)
        ob[(size_t)(brow0 + r) * 512 + kc * 64 + t * 16 + ln] = acc[kc * 4 + t][r];
    if (kc < 7) {
      unsigned short* nxt = ks[(kc + 1) & 1];
      const unsigned short* xs = (const unsigned short*)&vr0;
#pragma unroll
      for (int j = 0; j < 8; ++j) {
        int d = se + j;
        nxt[d * 72 + (si ^ (((d >> 3) & 7) << 3))] = xs[j];
      }
      xs = (const unsigned short*)&vr1;
#pragma unroll
      for (int j = 0; j < 8; ++j) {
        int d = se + j;
        nxt[d * 72 + ((si + 32) ^ (((d >> 3) & 7) << 3))] = xs[j];
      }
      __syncthreads();
    }
  }
#pragma unroll
  for (int ct = 0; ct < 4; ++ct)
#pragma unroll
    for (int r = 0; r < 4; ++r) {
      int m = b * 512 + qt * 64 + wid * 16 + quad * 4 + r;
      int cc = h * 64 + ct * 16 + ln;
      attnout[(size_t)m * 768 + cc] = f2bf(acc_o[ct][r]);
    }
}

extern "C" void kernel_launch(void* const* d_in, const int* in_sizes, int n_in,
                              void* d_out, int out_size, void* d_ws, size_t ws_size,
                              hipStream_t stream) {
  const float* features = (const float*)d_in[0];
  const float* boxes    = (const float*)d_in[1];
  const int*   isz      = (const int*)d_in[2];
  const float* Wq = (const float*)d_in[3];
  const float* bq = (const float*)d_in[4];
  const float* Wk = (const float*)d_in[5];
  const float* bk = (const float*)d_in[6];
  const float* Wv = (const float*)d_in[7];
  const float* bv = (const float*)d_in[8];
  const float* Wo = (const float*)d_in[9];
  const float* bo = (const float*)d_in[10];
  const float* gamma = (const float*)d_in[11];
  const float* beta  = (const float*)d_in[12];
  const float* dist_emb = (const float*)d_in[13];

  float* out = (float*)d_out;                   // (B,N,D) = 8192*768 f32
  float* att = out + (size_t)8192 * 768;        // (B,H,N,N) f32

  char* w = (char*)d_ws;
  unsigned short* ppk = (unsigned short*)w;     w += 8192 * 2;
  unsigned short* x = (unsigned short*)w;       w += (size_t)8192 * 768 * 2;
  unsigned short* wcat = (unsigned short*)w;    w += (size_t)2304 * 768 * 2;
  unsigned short* wo = (unsigned short*)w;      w += (size_t)768 * 768 * 2;
  float* bcat = (float*)w;                      w += 2304 * 4;
  unsigned short* qkv = (unsigned short*)w;     w += (size_t)8192 * 2304 * 2;
  unsigned short* attnout = (unsigned short*)w; w += (size_t)8192 * 768 * 2;

  pxpy_kernel<<<32, 256, 0, stream>>>(boxes, isz, ppk);
  ln_kernel<<<8192, 256, 0, stream>>>(features, gamma, beta, x);
  wprep_kernel<<<9216, 256, 0, stream>>>(Wq, Wk, Wv, Wo, bq, bk, bv, wcat, wo, bcat);
  gemm_bt<false><<<dim3(64, 18), 256, 0, stream>>>(x, wcat, bcat, qkv, 768, 2304);
  attn_fused<<<1536, 256, 0, stream>>>(qkv, ppk, dist_emb, att, attnout);
  gemm_bt<true><<<dim3(64, 6), 256, 0, stream>>>(attnout, wo, bo, out, 768, 768);
}